// Round 1
// 502.662 us; speedup vs baseline: 1.1169x; 1.1169x over previous
//
#include <hip/hip_runtime.h>
#include <cstdint>
#include <cstddef>

#define MDIM 8192
#define NDIM 4096
#define KDIM 4096

typedef __attribute__((ext_vector_type(8))) __bf16 bf16x8;
typedef __attribute__((ext_vector_type(4))) float floatx4;

typedef __attribute__((address_space(3))) void lds_t;
typedef __attribute__((address_space(1))) void glb_t;

__device__ __forceinline__ unsigned short f32_to_bf16(float f) {
  unsigned int u = __float_as_uint(f);
  u += 0x7FFFu + ((u >> 16) & 1u);   // RNE
  return (unsigned short)(u >> 16);
}

// e2m1 magnitude for code c in 0..7: {0,0.5,1,1.5,2,3,4,6}
__device__ __forceinline__ float fp4_mag(int c) {
  int e = (c >> 1) & 3, m = c & 1;
  int sh = e ? (e - 1) : 0;
  return e ? 0.5f * (float)((2 + m) << sh) : 0.5f * (float)m;
}

// ---------------- prepass 1: x fp32 -> bf16 ----------------
__global__ __launch_bounds__(256) void conv_x_kernel(const float* __restrict__ x,
                                                     unsigned short* __restrict__ xb) {
  const int t = blockIdx.x * 256 + threadIdx.x;     // 0 .. 4194303, 8 elems each
  const float4* src = (const float4*)x + (size_t)t * 2;
  float4 a = src[0], b = src[1];
  union { unsigned short us[8]; uint4 u4; } o;
  o.us[0] = f32_to_bf16(a.x); o.us[1] = f32_to_bf16(a.y);
  o.us[2] = f32_to_bf16(a.z); o.us[3] = f32_to_bf16(a.w);
  o.us[4] = f32_to_bf16(b.x); o.us[5] = f32_to_bf16(b.y);
  o.us[6] = f32_to_bf16(b.z); o.us[7] = f32_to_bf16(b.w);
  ((uint4*)xb)[t] = o.u4;
}

// ---------------- prepass 2: dequant weights -> bf16 [N][K] ----------------
__global__ __launch_bounds__(256) void dequant_kernel(const int* __restrict__ packed,
                                                      const float* __restrict__ scales,
                                                      unsigned short* __restrict__ wb) {
  const int t = blockIdx.x * 256 + threadIdx.x;     // 0 .. 1048575
  const int4* p = (const int4*)packed + (size_t)t * 2;
  int4 pa = p[0], pb = p[1];
  float s = scales[t];
  int bytes[8] = {pa.x, pa.y, pa.z, pa.w, pb.x, pb.y, pb.z, pb.w};
  union { unsigned short us[16]; uint4 u4[2]; } o;
#pragma unroll
  for (int i = 0; i < 8; ++i) {
    int by = bytes[i] & 255;
    int hi = by >> 4, lo = by & 15;                 // even idx = high nibble
    float vh = fp4_mag(hi & 7) * s; if (hi & 8) vh = -vh;
    float vl = fp4_mag(lo & 7) * s; if (lo & 8) vl = -vl;
    o.us[2 * i]     = f32_to_bf16(vh);
    o.us[2 * i + 1] = f32_to_bf16(vl);
  }
  uint4* dst = (uint4*)(wb + (size_t)t * 16);
  dst[0] = o.u4[0]; dst[1] = o.u4[1];
}

// ---------------- main GEMM: C[M,N] = A[M,K] * B[N,K]^T + bias ----------------
// 256x256 tile, BK=32, 8 waves (2x4), 4-deep circular LDS buffer (128 KiB),
// counted s_waitcnt vmcnt(12) deep pipeline (3 K-tiles in flight, never drained
// in main loop), raw s_barrier, XOR bank-swizzle applied via pre-swizzled
// global source (global_load_lds dest must stay linear) + swizzled ds_read,
// s_setprio around the MFMA cluster, XCD-aware block swizzle.
//
// Swizzle: LDS slot byte d holds tile byte b = d ^ (((d>>7)&7)<<4).
// XOR hits bits 4-6 only, f() depends on bits 7-9 only -> involution.
// Read side: for tile byte (row*64 + quad*16), f = ((row>>1)&7)<<4 and
// row bits 1..3 == r16 bits 1..3 (frag row = wr*128 + i*16 + r16), so the
// read XOR constant is uniform across i/j -> offsets are base + i*1024 B.
__global__ __launch_bounds__(512) void gemm256_kernel(const __bf16* __restrict__ A,
                                                      const __bf16* __restrict__ B,
                                                      const float* __restrict__ bias,
                                                      float* __restrict__ C) {
  __shared__ __bf16 ldsbuf[65536];          // 128 KiB = A[4][8192] + B[4][8192]
  __bf16* As = ldsbuf;
  __bf16* Bs = ldsbuf + 32768;

  const int t = threadIdx.x;
  const int wave = t >> 6, lane = t & 63;
  const int quad = lane >> 4, r16 = lane & 15;
  const int wr = wave >> 2, wc = wave & 3;  // 2 (M) x 4 (N) wave grid

  // T1: XCD swizzle. 512 wgs, 8 XCDs -> 64 wgs/XCD; n-fastest inside an XCD
  // so 16 consecutive wgs share one 2 MB A row-panel in that XCD's L2.
  const int bid = blockIdx.x;
  const int wg = (bid & 7) * 64 + (bid >> 3);
  const int m0 = (wg >> 4) * 256, n0 = (wg & 15) * 256;

  // ---- staging source addresses (inverse-swizzled global, linear LDS dest) ----
  const int swzS = ((t >> 3) & 7) << 4;
  const int b0 = (t * 16) ^ swzS;            // load j=0: slot d = t*16
  const int b1 = (8192 + t * 16) ^ swzS;     // load j=1: slot d = 8192 + t*16
  const int row0 = b0 >> 6, col0 = (b0 & 63) >> 1;   // col is multiple of 8 elems
  const int row1 = b1 >> 6, col1 = (b1 & 63) >> 1;   // row1 in [128,256)

  const __bf16* pa0 = A + (size_t)(m0 + row0) * KDIM + col0;
  const __bf16* pa1 = A + (size_t)(m0 + row1) * KDIM + col1;
  const __bf16* pb0 = B + (size_t)(n0 + row0) * KDIM + col0;
  const __bf16* pb1 = B + (size_t)(n0 + row1) * KDIM + col1;

  // ---- swizzled LDS read offsets (element units) ----
  const int swzR = ((r16 >> 1) & 7) << 4;
  const int offAe = ((((wr * 128 + r16) * 64) + quad * 16) ^ swzR) >> 1;
  const int offBe = ((((wc * 64  + r16) * 64) + quad * 16) ^ swzR) >> 1;

  floatx4 acc[8][4] = {};

#define STAGE(TT) do {                                                                              \
    const int _kk = (TT) * 32;                                                                      \
    __bf16* _ab = As + ((TT) & 3) * 8192;                                                           \
    __bf16* _bb = Bs + ((TT) & 3) * 8192;                                                           \
    __builtin_amdgcn_global_load_lds((const glb_t*)(pa0 + _kk), (lds_t*)(_ab + wave * 512), 16, 0, 0);        \
    __builtin_amdgcn_global_load_lds((const glb_t*)(pa1 + _kk), (lds_t*)(_ab + 4096 + wave * 512), 16, 0, 0); \
    __builtin_amdgcn_global_load_lds((const glb_t*)(pb0 + _kk), (lds_t*)(_bb + wave * 512), 16, 0, 0);        \
    __builtin_amdgcn_global_load_lds((const glb_t*)(pb1 + _kk), (lds_t*)(_bb + 4096 + wave * 512), 16, 0, 0); \
  } while (0)

#define BARRIER() asm volatile("s_barrier" ::: "memory")

#define COMPUTE(TT) do {                                                          \
    const __bf16* _a = As + ((TT) & 3) * 8192;                                    \
    const __bf16* _b = Bs + ((TT) & 3) * 8192;                                    \
    bf16x8 af[8], bfv[4];                                                         \
    _Pragma("unroll")                                                             \
    for (int i = 0; i < 8; ++i) af[i] = *(const bf16x8*)(_a + offAe + i * 512);   \
    _Pragma("unroll")                                                             \
    for (int j = 0; j < 4; ++j) bfv[j] = *(const bf16x8*)(_b + offBe + j * 512);  \
    __builtin_amdgcn_s_setprio(1);                                                \
    _Pragma("unroll")                                                             \
    for (int i = 0; i < 8; ++i) {                                                 \
      _Pragma("unroll")                                                           \
      for (int j = 0; j < 4; ++j)                                                 \
        acc[i][j] = __builtin_amdgcn_mfma_f32_16x16x32_bf16(af[i], bfv[j], acc[i][j], 0, 0, 0); \
    }                                                                             \
    __builtin_amdgcn_s_setprio(0);                                                \
    BARRIER();                                                                    \
  } while (0)

  // Prologue: 3 tiles in flight.
  STAGE(0); STAGE(1); STAGE(2);

  // Main loop. STAGE(T+3) targets buf[(T-1)&3], whose last reads (tile T-1's
  // ds_reads) completed before the barrier that ended iteration T-1 -> no race.
  // vmcnt(12) = 4 loads/tile x 3 tiles outstanding -> tile T fully landed.
  for (int T = 0; T < 125; ++T) {
    STAGE(T + 3);
    asm volatile("s_waitcnt vmcnt(12)" ::: "memory");
    BARRIER();
    COMPUTE(T);
  }
  // Epilogue drain: 8 -> 4 -> 0.
  asm volatile("s_waitcnt vmcnt(8)" ::: "memory");
  BARRIER();
  COMPUTE(125);
  asm volatile("s_waitcnt vmcnt(4)" ::: "memory");
  BARRIER();
  COMPUTE(126);
  asm volatile("s_waitcnt vmcnt(0)" ::: "memory");
  BARRIER();
  COMPUTE(127);

#undef STAGE
#undef BARRIER
#undef COMPUTE

  // epilogue: C/D layout col = lane&15, row = quad*4 + reg
  float bv[4];
#pragma unroll
  for (int j = 0; j < 4; ++j) bv[j] = bias[n0 + wc * 64 + j * 16 + r16];
#pragma unroll
  for (int i = 0; i < 8; ++i) {
    const int gm = m0 + wr * 128 + i * 16 + quad * 4;
#pragma unroll
    for (int j = 0; j < 4; ++j) {
      float* cp = C + (size_t)gm * NDIM + (n0 + wc * 64 + j * 16 + r16);
#pragma unroll
      for (int r = 0; r < 4; ++r)
        cp[(size_t)r * NDIM] = acc[i][j][r] + bv[j];
    }
  }
}

// ---------------- fallback (ws too small): fused naive ----------------
__global__ __launch_bounds__(256) void fused_fallback(const float* __restrict__ x,
                                                      const int* __restrict__ packed,
                                                      const float* __restrict__ scales,
                                                      const float* __restrict__ bias,
                                                      float* __restrict__ out) {
  const int n = blockIdx.x * 256 + threadIdx.x;
  const int m = blockIdx.y;
  const float* xr = x + (size_t)m * KDIM;
  const int* pr = packed + (size_t)n * (KDIM / 2);
  const float* sc = scales + (size_t)n * (KDIM / 16);
  float acc = 0.f;
  for (int kb = 0; kb < KDIM / 16; ++kb) {
    float s = sc[kb];
    float part = 0.f;
#pragma unroll
    for (int i = 0; i < 8; ++i) {
      int by = pr[kb * 8 + i] & 255;
      int hi = by >> 4, lo = by & 15;
      float vh = fp4_mag(hi & 7); if (hi & 8) vh = -vh;
      float vl = fp4_mag(lo & 7); if (lo & 8) vl = -vl;
      part += xr[kb * 16 + 2 * i] * vh + xr[kb * 16 + 2 * i + 1] * vl;
    }
    acc += s * part;
  }
  out[(size_t)m * NDIM + n] = acc + bias[n];
}

extern "C" void kernel_launch(void* const* d_in, const int* in_sizes, int n_in,
                              void* d_out, int out_size, void* d_ws, size_t ws_size,
                              hipStream_t stream) {
  const float* x      = (const float*)d_in[0];
  const int*   packed = (const int*)d_in[1];
  const float* scales = (const float*)d_in[2];
  const float* bias   = (const float*)d_in[3];
  float* out = (float*)d_out;

  const size_t needA = (size_t)MDIM * KDIM * 2;   // 64 MB bf16 x
  const size_t needW = (size_t)NDIM * KDIM * 2;   // 32 MB bf16 w

  if (ws_size >= needA + needW) {
    unsigned short* xb = (unsigned short*)d_ws;
    unsigned short* wb = (unsigned short*)((char*)d_ws + needA);
    conv_x_kernel<<<(MDIM * KDIM / 8) / 256, 256, 0, stream>>>(x, xb);
    dequant_kernel<<<(NDIM * KDIM / 16) / 256, 256, 0, stream>>>(packed, scales, wb);
    dim3 grid((MDIM / 256) * (NDIM / 256));       // 512 wgs, XCD-swizzled in-kernel
    gemm256_kernel<<<grid, 512, 0, stream>>>((const __bf16*)xb, (const __bf16*)wb, bias, out);
  } else {
    dim3 grid(NDIM / 256, MDIM);
    fused_fallback<<<grid, 256, 0, stream>>>(x, packed, scales, bias, out);
  }
}

// Round 2
// 493.151 us; speedup vs baseline: 1.1385x; 1.0193x over previous
//
#include <hip/hip_runtime.h>
#include <cstdint>
#include <cstddef>

#define MDIM 8192
#define NDIM 4096
#define KDIM 4096

typedef __attribute__((ext_vector_type(8))) __bf16 bf16x8;
typedef __attribute__((ext_vector_type(4))) float floatx4;

typedef __attribute__((address_space(3))) void lds_t;
typedef __attribute__((address_space(1))) void glb_t;

__device__ __forceinline__ unsigned short f32_to_bf16(float f) {
  unsigned int u = __float_as_uint(f);
  u += 0x7FFFu + ((u >> 16) & 1u);   // RNE
  return (unsigned short)(u >> 16);
}

// e2m1 magnitude for code c in 0..7: {0,0.5,1,1.5,2,3,4,6}
__device__ __forceinline__ float fp4_mag(int c) {
  int e = (c >> 1) & 3, m = c & 1;
  int sh = e ? (e - 1) : 0;
  return e ? 0.5f * (float)((2 + m) << sh) : 0.5f * (float)m;
}

// ---------------- prepass 1: x fp32 -> bf16 ----------------
__global__ __launch_bounds__(256) void conv_x_kernel(const float* __restrict__ x,
                                                     unsigned short* __restrict__ xb) {
  const int t = blockIdx.x * 256 + threadIdx.x;     // 0 .. 4194303, 8 elems each
  const float4* src = (const float4*)x + (size_t)t * 2;
  float4 a = src[0], b = src[1];
  union { unsigned short us[8]; uint4 u4; } o;
  o.us[0] = f32_to_bf16(a.x); o.us[1] = f32_to_bf16(a.y);
  o.us[2] = f32_to_bf16(a.z); o.us[3] = f32_to_bf16(a.w);
  o.us[4] = f32_to_bf16(b.x); o.us[5] = f32_to_bf16(b.y);
  o.us[6] = f32_to_bf16(b.z); o.us[7] = f32_to_bf16(b.w);
  ((uint4*)xb)[t] = o.u4;
}

// ---------------- prepass 2: dequant weights -> bf16 [N][K] ----------------
__global__ __launch_bounds__(256) void dequant_kernel(const int* __restrict__ packed,
                                                      const float* __restrict__ scales,
                                                      unsigned short* __restrict__ wb) {
  const int t = blockIdx.x * 256 + threadIdx.x;     // 0 .. 1048575
  const int4* p = (const int4*)packed + (size_t)t * 2;
  int4 pa = p[0], pb = p[1];
  float s = scales[t];
  int bytes[8] = {pa.x, pa.y, pa.z, pa.w, pb.x, pb.y, pb.z, pb.w};
  union { unsigned short us[16]; uint4 u4[2]; } o;
#pragma unroll
  for (int i = 0; i < 8; ++i) {
    int by = bytes[i] & 255;
    int hi = by >> 4, lo = by & 15;                 // even idx = high nibble
    float vh = fp4_mag(hi & 7) * s; if (hi & 8) vh = -vh;
    float vl = fp4_mag(lo & 7) * s; if (lo & 8) vl = -vl;
    o.us[2 * i]     = f32_to_bf16(vh);
    o.us[2 * i + 1] = f32_to_bf16(vl);
  }
  uint4* dst = (uint4*)(wb + (size_t)t * 16);
  dst[0] = o.u4[0]; dst[1] = o.u4[1];
}

// ---------------- main GEMM: C[M,N] = A[M,K] * B[N,K]^T + bias ----------------
// 256x256 tile, BK=32, 8 waves (2x4), 4-deep LDS ring (128 KiB), m201-style
// 2-phase-per-K-tile schedule: each phase = {ds_reads ; 1 half-tile
// global_load_lds ; s_barrier ; lgkmcnt(0)+sched_barrier ; setprio(1) ;
// 16 MFMA ; setprio(0) ; [vmcnt(8) at end of tile] ; s_barrier}.
// Counted vmcnt never drains to 0 in the main loop (T4); phase split gives
// waves a role-split so setprio pays (T5 gated by T3).
//
// Swizzle (verified r1, 0 bank conflicts): LDS slot byte d holds tile byte
// b = d ^ (((d>>7)&7)<<4); staging pre-swizzles the GLOBAL source address
// (global_load_lds dest must stay linear), reads XOR the same function.
__global__ __launch_bounds__(512, 2) void gemm256_kernel(const __bf16* __restrict__ A,
                                                         const __bf16* __restrict__ B,
                                                         const float* __restrict__ bias,
                                                         float* __restrict__ C) {
  __shared__ __bf16 ldsbuf[65536];          // 128 KiB = A[4][8192] + B[4][8192]
  __bf16* As = ldsbuf;
  __bf16* Bs = ldsbuf + 32768;

  const int t = threadIdx.x;
  const int wave = t >> 6, lane = t & 63;
  const int quad = lane >> 4, r16 = lane & 15;
  const int wr = wave >> 2, wc = wave & 3;  // 2 (M) x 4 (N) wave grid

  // T1: XCD swizzle. 512 wgs, 8 XCDs -> 64 wgs/XCD; n-fastest inside an XCD.
  const int bid = blockIdx.x;
  const int wg = (bid & 7) * 64 + (bid >> 3);
  const int m0 = (wg >> 4) * 256, n0 = (wg & 15) * 256;

  // ---- staging source addresses (inverse-swizzled global, linear LDS dest) ----
  const int swzS = ((t >> 3) & 7) << 4;
  const int b0 = (t * 16) ^ swzS;            // load j=0: slot d = t*16
  const int b1 = (8192 + t * 16) ^ swzS;     // load j=1: slot d = 8192 + t*16
  const int row0 = b0 >> 6, col0 = (b0 & 63) >> 1;
  const int row1 = b1 >> 6, col1 = (b1 & 63) >> 1;   // row1 in [128,256)

  const __bf16* pa0 = A + (size_t)(m0 + row0) * KDIM + col0;
  const __bf16* pa1 = A + (size_t)(m0 + row1) * KDIM + col1;
  const __bf16* pb0 = B + (size_t)(n0 + row0) * KDIM + col0;
  const __bf16* pb1 = B + (size_t)(n0 + row1) * KDIM + col1;

  // ---- swizzled LDS read offsets (element units) ----
  const int swzR = ((r16 >> 1) & 7) << 4;
  const int offAe = ((((wr * 128 + r16) * 64) + quad * 16) ^ swzR) >> 1;
  const int offBe = ((((wc * 64  + r16) * 64) + quad * 16) ^ swzR) >> 1;

  floatx4 acc[8][4] = {};

  // ---- prologue: stage tiles 0,1,2 (A,A,B,B order per tile) ----
#pragma unroll
  for (int p = 0; p < 3; ++p) {
    __bf16* _ab = As + p * 8192;
    __bf16* _bb = Bs + p * 8192;
    __builtin_amdgcn_global_load_lds((const glb_t*)(pa0 + p * 32), (lds_t*)(_ab + wave * 512), 16, 0, 0);
    __builtin_amdgcn_global_load_lds((const glb_t*)(pa1 + p * 32), (lds_t*)(_ab + 4096 + wave * 512), 16, 0, 0);
    __builtin_amdgcn_global_load_lds((const glb_t*)(pb0 + p * 32), (lds_t*)(_bb + wave * 512), 16, 0, 0);
    __builtin_amdgcn_global_load_lds((const glb_t*)(pb1 + p * 32), (lds_t*)(_bb + 4096 + wave * 512), 16, 0, 0);
  }
  asm volatile("s_waitcnt vmcnt(8)" ::: "memory");   // tile 0 fully landed
  __builtin_amdgcn_s_barrier();

  const __bf16* sa0 = pa0 + 96;   // staging cursor: tile 3
  const __bf16* sa1 = pa1 + 96;
  const __bf16* sb0 = pb0 + 96;
  const __bf16* sb1 = pb1 + 96;

#define TILE(TT, DO_STAGE, VMASM) do {                                            \
    const __bf16* _a = As + ((TT) & 3) * 8192;                                    \
    const __bf16* _b = Bs + ((TT) & 3) * 8192;                                    \
    __bf16* _sa = As + (((TT) + 3) & 3) * 8192;                                   \
    __bf16* _sb = Bs + (((TT) + 3) & 3) * 8192;                                   \
    bf16x8 af[4], bfv[4];                                                         \
    /* ---------- phase A ---------- */                                           \
    _Pragma("unroll")                                                             \
    for (int i = 0; i < 4; ++i) af[i] = *(const bf16x8*)(_a + offAe + i * 512);   \
    _Pragma("unroll")                                                             \
    for (int j = 0; j < 4; ++j) bfv[j] = *(const bf16x8*)(_b + offBe + j * 512);  \
    if (DO_STAGE) {                                                               \
      __builtin_amdgcn_global_load_lds((const glb_t*)sa0, (lds_t*)(_sa + wave * 512), 16, 0, 0);        \
      __builtin_amdgcn_global_load_lds((const glb_t*)sa1, (lds_t*)(_sa + 4096 + wave * 512), 16, 0, 0); \
    }                                                                             \
    __builtin_amdgcn_s_barrier();                                                 \
    asm volatile("s_waitcnt lgkmcnt(0)" ::: "memory");                            \
    __builtin_amdgcn_sched_barrier(0);                                            \
    __builtin_amdgcn_s_setprio(1);                                                \
    _Pragma("unroll")                                                             \
    for (int i = 0; i < 4; ++i) {                                                 \
      _Pragma("unroll")                                                           \
      for (int j = 0; j < 4; ++j)                                                 \
        acc[i][j] = __builtin_amdgcn_mfma_f32_16x16x32_bf16(af[i], bfv[j], acc[i][j], 0, 0, 0); \
    }                                                                             \
    __builtin_amdgcn_s_setprio(0);                                                \
    __builtin_amdgcn_s_barrier();                                                 \
    /* ---------- phase B ---------- */                                           \
    _Pragma("unroll")                                                             \
    for (int i = 0; i < 4; ++i) af[i] = *(const bf16x8*)(_a + offAe + (4 + i) * 512); \
    if (DO_STAGE) {                                                               \
      __builtin_amdgcn_global_load_lds((const glb_t*)sb0, (lds_t*)(_sb + wave * 512), 16, 0, 0);        \
      __builtin_amdgcn_global_load_lds((const glb_t*)sb1, (lds_t*)(_sb + 4096 + wave * 512), 16, 0, 0); \
    }                                                                             \
    __builtin_amdgcn_s_barrier();                                                 \
    asm volatile("s_waitcnt lgkmcnt(0)" ::: "memory");                            \
    __builtin_amdgcn_sched_barrier(0);                                            \
    __builtin_amdgcn_s_setprio(1);                                                \
    _Pragma("unroll")                                                             \
    for (int i = 0; i < 4; ++i) {                                                 \
      _Pragma("unroll")                                                           \
      for (int j = 0; j < 4; ++j)                                                 \
        acc[4 + i][j] = __builtin_amdgcn_mfma_f32_16x16x32_bf16(af[i], bfv[j], acc[4 + i][j], 0, 0, 0); \
    }                                                                             \
    __builtin_amdgcn_s_setprio(0);                                                \
    VMASM;                                                                        \
    __builtin_amdgcn_s_barrier();                                                 \
  } while (0)

  // Main loop: tiles 0..124, staging tiles 3..127, vmcnt(8) once per tile
  // (8 = 2 loads/thread/phase x 4 phases of slack -> tile T+1 fully landed).
  for (int T = 0; T < 125; ++T) {
    TILE(T, true, asm volatile("s_waitcnt vmcnt(8)" ::: "memory"));
    sa0 += 32; sa1 += 32; sb0 += 32; sb1 += 32;
  }
  // Epilogue drain: 4 -> 0.
  TILE(125, false, asm volatile("s_waitcnt vmcnt(4)" ::: "memory"));
  TILE(126, false, asm volatile("s_waitcnt vmcnt(0)" ::: "memory"));
  TILE(127, false, (void)0);

#undef TILE

  // epilogue: C/D layout col = lane&15, row = quad*4 + reg
  float bv[4];
#pragma unroll
  for (int j = 0; j < 4; ++j) bv[j] = bias[n0 + wc * 64 + j * 16 + r16];
#pragma unroll
  for (int i = 0; i < 8; ++i) {
    const int gm = m0 + wr * 128 + i * 16 + quad * 4;
#pragma unroll
    for (int j = 0; j < 4; ++j) {
      float* cp = C + (size_t)gm * NDIM + (n0 + wc * 64 + j * 16 + r16);
#pragma unroll
      for (int r = 0; r < 4; ++r)
        cp[(size_t)r * NDIM] = acc[i][j][r] + bv[j];
    }
  }
}

// ---------------- fallback (ws too small): fused naive ----------------
__global__ __launch_bounds__(256) void fused_fallback(const float* __restrict__ x,
                                                      const int* __restrict__ packed,
                                                      const float* __restrict__ scales,
                                                      const float* __restrict__ bias,
                                                      float* __restrict__ out) {
  const int n = blockIdx.x * 256 + threadIdx.x;
  const int m = blockIdx.y;
  const float* xr = x + (size_t)m * KDIM;
  const int* pr = packed + (size_t)n * (KDIM / 2);
  const float* sc = scales + (size_t)n * (KDIM / 16);
  float acc = 0.f;
  for (int kb = 0; kb < KDIM / 16; ++kb) {
    float s = sc[kb];
    float part = 0.f;
#pragma unroll
    for (int i = 0; i < 8; ++i) {
      int by = pr[kb * 8 + i] & 255;
      int hi = by >> 4, lo = by & 15;
      float vh = fp4_mag(hi & 7); if (hi & 8) vh = -vh;
      float vl = fp4_mag(lo & 7); if (lo & 8) vl = -vl;
      part += xr[kb * 16 + 2 * i] * vh + xr[kb * 16 + 2 * i + 1] * vl;
    }
    acc += s * part;
  }
  out[(size_t)m * NDIM + n] = acc + bias[n];
}

extern "C" void kernel_launch(void* const* d_in, const int* in_sizes, int n_in,
                              void* d_out, int out_size, void* d_ws, size_t ws_size,
                              hipStream_t stream) {
  const float* x      = (const float*)d_in[0];
  const int*   packed = (const int*)d_in[1];
  const float* scales = (const float*)d_in[2];
  const float* bias   = (const float*)d_in[3];
  float* out = (float*)d_out;

  const size_t needA = (size_t)MDIM * KDIM * 2;   // 64 MB bf16 x
  const size_t needW = (size_t)NDIM * KDIM * 2;   // 32 MB bf16 w

  if (ws_size >= needA + needW) {
    unsigned short* xb = (unsigned short*)d_ws;
    unsigned short* wb = (unsigned short*)((char*)d_ws + needA);
    conv_x_kernel<<<(MDIM * KDIM / 8) / 256, 256, 0, stream>>>(x, xb);
    dequant_kernel<<<(NDIM * KDIM / 16) / 256, 256, 0, stream>>>(packed, scales, wb);
    dim3 grid((MDIM / 256) * (NDIM / 256));       // 512 wgs, XCD-swizzled in-kernel
    gemm256_kernel<<<grid, 512, 0, stream>>>((const __bf16*)xb, (const __bf16*)wb, bias, out);
  } else {
    dim3 grid(NDIM / 256, MDIM);
    fused_fallback<<<grid, 256, 0, stream>>>(x, packed, scales, bias, out);
  }
}

// Round 4
// 479.231 us; speedup vs baseline: 1.1715x; 1.0290x over previous
//
#include <hip/hip_runtime.h>
#include <cstdint>
#include <cstddef>

#define MDIM 8192
#define NDIM 4096
#define KDIM 4096

// NOTE: resubmission of the round-3 kernel — the previous bench died with
// "MI355X container failed twice" (infra), so the pipelined schedule below
// was never measured. Hazard audit in the gemm256_kernel comment.

typedef __attribute__((ext_vector_type(8))) __bf16 bf16x8;
typedef __attribute__((ext_vector_type(4))) float floatx4;

typedef __attribute__((address_space(3))) void lds_t;
typedef __attribute__((address_space(1))) void glb_t;

__device__ __forceinline__ unsigned short f32_to_bf16(float f) {
  unsigned int u = __float_as_uint(f);
  u += 0x7FFFu + ((u >> 16) & 1u);   // RNE
  return (unsigned short)(u >> 16);
}

// e2m1 magnitude for code c in 0..7: {0,0.5,1,1.5,2,3,4,6}
__device__ __forceinline__ float fp4_mag(int c) {
  int e = (c >> 1) & 3, m = c & 1;
  int sh = e ? (e - 1) : 0;
  return e ? 0.5f * (float)((2 + m) << sh) : 0.5f * (float)m;
}

// ---------------- prepass 1: x fp32 -> bf16 ----------------
__global__ __launch_bounds__(256) void conv_x_kernel(const float* __restrict__ x,
                                                     unsigned short* __restrict__ xb) {
  const int t = blockIdx.x * 256 + threadIdx.x;     // 0 .. 4194303, 8 elems each
  const float4* src = (const float4*)x + (size_t)t * 2;
  float4 a = src[0], b = src[1];
  union { unsigned short us[8]; uint4 u4; } o;
  o.us[0] = f32_to_bf16(a.x); o.us[1] = f32_to_bf16(a.y);
  o.us[2] = f32_to_bf16(a.z); o.us[3] = f32_to_bf16(a.w);
  o.us[4] = f32_to_bf16(b.x); o.us[5] = f32_to_bf16(b.y);
  o.us[6] = f32_to_bf16(b.z); o.us[7] = f32_to_bf16(b.w);
  ((uint4*)xb)[t] = o.u4;
}

// ---------------- prepass 2: dequant weights -> bf16 [N][K] ----------------
__global__ __launch_bounds__(256) void dequant_kernel(const int* __restrict__ packed,
                                                      const float* __restrict__ scales,
                                                      unsigned short* __restrict__ wb) {
  const int t = blockIdx.x * 256 + threadIdx.x;     // 0 .. 1048575
  const int4* p = (const int4*)packed + (size_t)t * 2;
  int4 pa = p[0], pb = p[1];
  float s = scales[t];
  int bytes[8] = {pa.x, pa.y, pa.z, pa.w, pb.x, pb.y, pb.z, pb.w};
  union { unsigned short us[16]; uint4 u4[2]; } o;
#pragma unroll
  for (int i = 0; i < 8; ++i) {
    int by = bytes[i] & 255;
    int hi = by >> 4, lo = by & 15;                 // even idx = high nibble
    float vh = fp4_mag(hi & 7) * s; if (hi & 8) vh = -vh;
    float vl = fp4_mag(lo & 7) * s; if (lo & 8) vl = -vl;
    o.us[2 * i]     = f32_to_bf16(vh);
    o.us[2 * i + 1] = f32_to_bf16(vl);
  }
  uint4* dst = (uint4*)(wb + (size_t)t * 16);
  dst[0] = o.u4[0]; dst[1] = o.u4[1];
}

// ---------------- main GEMM: C[M,N] = A[M,K] * B[N,K]^T + bias ----------------
// 256x256 tile, BK=32, 8 waves (2x4), 4-deep LDS ring (128 KiB).
// PIPELINED 2-phase schedule: ds_reads issued in phase p feed phase p+1's
// MFMA, so the LDS drain overlaps the matrix pipe instead of serializing
// behind lgkmcnt(0). Compiler inserts minimal COUNTED lgkm waits for the
// cross-phase register deps (plain C++ ds_reads, not inline asm).
//   PH_A(T): issue afB(T) reads [buf T] + stage(T+3, A-matrix);
//            MFMA acc[0..3] += afA(T) x bfv(T);  vmcnt(6); s_barrier
//   PH_B(T): issue afA(T+1), bfvN(T+1) reads [buf T+1] + stage(T+3, B-matrix);
//            MFMA acc[4..7] += afB(T) x bfv(T);  s_barrier
// vmcnt(6) at end of PH_A(T) drains tile T+1's 4 loads (issued 2 tiles ago ->
// wait-free) before PH_B pre-reads buf[(T+1)&3]. Stage(T+3) overwrites
// buf[(T-1)&3]; the last reads of that buffer were waited (compiler lgkm)
// before PH_B(T-1)'s MFMA, and the end-of-B barrier orders all waves before
// the stage issues -> no WAR race. Reads issued in PH_B(T) complete before
// their use in PH_A(T+1) MFMA, two barriers before buf[(T+1)&3] is restaged
// in PH_A(T+2). bfv ping-pongs via 2-tile loop unroll (static reg names).
//
// Swizzle (verified r1, 0 bank conflicts): LDS slot byte d holds tile byte
// b = d ^ (((d>>7)&7)<<4); staging pre-swizzles the GLOBAL source address
// (global_load_lds dest must stay linear), reads XOR the same function.
__global__ __launch_bounds__(512, 2) void gemm256_kernel(const __bf16* __restrict__ A,
                                                         const __bf16* __restrict__ B,
                                                         const float* __restrict__ bias,
                                                         float* __restrict__ C) {
  __shared__ __bf16 ldsbuf[65536];          // 128 KiB = A[4][8192] + B[4][8192]
  __bf16* As = ldsbuf;
  __bf16* Bs = ldsbuf + 32768;

  const int t = threadIdx.x;
  const int wave = t >> 6, lane = t & 63;
  const int quad = lane >> 4, r16 = lane & 15;
  const int wr = wave >> 2, wc = wave & 3;  // 2 (M) x 4 (N) wave grid

  // T1: XCD swizzle. 512 wgs, 8 XCDs -> 64 wgs/XCD; n-fastest inside an XCD.
  const int bid = blockIdx.x;
  const int wg = (bid & 7) * 64 + (bid >> 3);
  const int m0 = (wg >> 4) * 256, n0 = (wg & 15) * 256;

  // ---- staging source addresses (inverse-swizzled global, linear LDS dest) ----
  const int swzS = ((t >> 3) & 7) << 4;
  const int b0 = (t * 16) ^ swzS;            // load j=0: slot d = t*16
  const int b1 = (8192 + t * 16) ^ swzS;     // load j=1: slot d = 8192 + t*16
  const int row0 = b0 >> 6, col0 = (b0 & 63) >> 1;
  const int row1 = b1 >> 6, col1 = (b1 & 63) >> 1;   // row1 in [128,256)

  const __bf16* pa0 = A + (size_t)(m0 + row0) * KDIM + col0;
  const __bf16* pa1 = A + (size_t)(m0 + row1) * KDIM + col1;
  const __bf16* pb0 = B + (size_t)(n0 + row0) * KDIM + col0;
  const __bf16* pb1 = B + (size_t)(n0 + row1) * KDIM + col1;

  // ---- swizzled LDS read offsets (element units) ----
  const int swzR = ((r16 >> 1) & 7) << 4;
  const int offAe = ((((wr * 128 + r16) * 64) + quad * 16) ^ swzR) >> 1;
  const int offBe = ((((wc * 64  + r16) * 64) + quad * 16) ^ swzR) >> 1;

  floatx4 acc[8][4] = {};
  bf16x8 afA[4], afB[4], bfv0[4], bfv1[4];

  // ---- prologue: stage tiles 0,1,2; issue order per tile = [Amat(2), Bmat(2)] ----
#pragma unroll
  for (int p = 0; p < 3; ++p) {
    __bf16* _ab = As + p * 8192;
    __bf16* _bb = Bs + p * 8192;
    __builtin_amdgcn_global_load_lds((const glb_t*)(pa0 + p * 32), (lds_t*)(_ab + wave * 512), 16, 0, 0);
    __builtin_amdgcn_global_load_lds((const glb_t*)(pa1 + p * 32), (lds_t*)(_ab + 4096 + wave * 512), 16, 0, 0);
    __builtin_amdgcn_global_load_lds((const glb_t*)(pb0 + p * 32), (lds_t*)(_bb + wave * 512), 16, 0, 0);
    __builtin_amdgcn_global_load_lds((const glb_t*)(pb1 + p * 32), (lds_t*)(_bb + 4096 + wave * 512), 16, 0, 0);
  }
  asm volatile("s_waitcnt vmcnt(8)" ::: "memory");   // tile 0 fully landed
  __builtin_amdgcn_s_barrier();

  // prime registers for tile 0 (waits auto-inserted before first MFMA use)
#pragma unroll
  for (int i = 0; i < 4; ++i) afA[i] = *(const bf16x8*)(As + offAe + i * 512);
#pragma unroll
  for (int j = 0; j < 4; ++j) bfv0[j] = *(const bf16x8*)(Bs + offBe + j * 512);

  const __bf16* sa0 = pa0 + 96;   // staging cursor: tile 3
  const __bf16* sa1 = pa1 + 96;
  const __bf16* sb0 = pb0 + 96;
  const __bf16* sb1 = pb1 + 96;

#define VM6 asm volatile("s_waitcnt vmcnt(6)" ::: "memory")
#define VM4 asm volatile("s_waitcnt vmcnt(4)" ::: "memory")
#define VM0 asm volatile("s_waitcnt vmcnt(0)" ::: "memory")
#define VMNONE (void)0

#define PH_A(TT, BV, DO_STAGE, SOFF, VMASM) do {                                  \
    const __bf16* _a = As + ((TT) & 3) * 8192;                                    \
    __bf16* _sa = As + (((TT) + 3) & 3) * 8192;                                   \
    _Pragma("unroll")                                                             \
    for (int i = 0; i < 4; ++i) afB[i] = *(const bf16x8*)(_a + offAe + (4 + i) * 512); \
    if (DO_STAGE) {                                                               \
      __builtin_amdgcn_global_load_lds((const glb_t*)(sa0 + (SOFF)), (lds_t*)(_sa + wave * 512), 16, 0, 0);        \
      __builtin_amdgcn_global_load_lds((const glb_t*)(sa1 + (SOFF)), (lds_t*)(_sa + 4096 + wave * 512), 16, 0, 0); \
    }                                                                             \
    __builtin_amdgcn_sched_barrier(0);                                            \
    __builtin_amdgcn_s_setprio(1);                                                \
    _Pragma("unroll")                                                             \
    for (int i = 0; i < 4; ++i) {                                                 \
      _Pragma("unroll")                                                           \
      for (int j = 0; j < 4; ++j)                                                 \
        acc[i][j] = __builtin_amdgcn_mfma_f32_16x16x32_bf16(afA[i], BV[j], acc[i][j], 0, 0, 0); \
    }                                                                             \
    __builtin_amdgcn_s_setprio(0);                                                \
    __builtin_amdgcn_sched_barrier(0);                                            \
    VMASM;                                                                        \
    __builtin_amdgcn_s_barrier();                                                 \
  } while (0)

#define PH_B(TT, BV, BVN, DO_STAGE, DO_NEXT, DO_BAR, SOFF) do {                   \
    const __bf16* _na = As + (((TT) + 1) & 3) * 8192;                             \
    const __bf16* _nb = Bs + (((TT) + 1) & 3) * 8192;                             \
    __bf16* _sb = Bs + (((TT) + 3) & 3) * 8192;                                   \
    if (DO_NEXT) {                                                                \
      _Pragma("unroll")                                                           \
      for (int i = 0; i < 4; ++i) afA[i] = *(const bf16x8*)(_na + offAe + i * 512);  \
      _Pragma("unroll")                                                           \
      for (int j = 0; j < 4; ++j) BVN[j] = *(const bf16x8*)(_nb + offBe + j * 512);  \
    }                                                                             \
    if (DO_STAGE) {                                                               \
      __builtin_amdgcn_global_load_lds((const glb_t*)(sb0 + (SOFF)), (lds_t*)(_sb + wave * 512), 16, 0, 0);        \
      __builtin_amdgcn_global_load_lds((const glb_t*)(sb1 + (SOFF)), (lds_t*)(_sb + 4096 + wave * 512), 16, 0, 0); \
    }                                                                             \
    __builtin_amdgcn_sched_barrier(0);                                            \
    __builtin_amdgcn_s_setprio(1);                                                \
    _Pragma("unroll")                                                             \
    for (int i = 0; i < 4; ++i) {                                                 \
      _Pragma("unroll")                                                           \
      for (int j = 0; j < 4; ++j)                                                 \
        acc[4 + i][j] = __builtin_amdgcn_mfma_f32_16x16x32_bf16(afB[i], BV[j], acc[4 + i][j], 0, 0, 0); \
    }                                                                             \
    __builtin_amdgcn_s_setprio(0);                                                \
    __builtin_amdgcn_sched_barrier(0);                                            \
    if (DO_BAR) __builtin_amdgcn_s_barrier();                                     \
  } while (0)

  // Main loop: tiles 0..123 (2-tile unroll for bfv ping-pong), staging T+3.
  for (int T = 0; T < 124; T += 2) {
    PH_A(T,     bfv0, true, 0,  VM6);
    PH_B(T,     bfv0, bfv1, true, true, true, 0);
    PH_A(T + 1, bfv1, true, 32, VM6);
    PH_B(T + 1, bfv1, bfv0, true, true, true, 32);
    sa0 += 64; sa1 += 64; sb0 += 64; sb1 += 64;
  }
  // Tail: T=124 stages tile 127; 125/126 drain vmcnt 4 -> 0; 127 computes only.
  PH_A(124, bfv0, true,  0, VM6);
  PH_B(124, bfv0, bfv1, true,  true, true, 0);
  PH_A(125, bfv1, false, 0, VM4);
  PH_B(125, bfv1, bfv0, false, true, true, 0);
  PH_A(126, bfv0, false, 0, VM0);
  PH_B(126, bfv0, bfv1, false, true, true, 0);
  PH_A(127, bfv1, false, 0, VMNONE);
  PH_B(127, bfv1, bfv0, false, false, false, 0);

#undef PH_A
#undef PH_B
#undef VM6
#undef VM4
#undef VM0
#undef VMNONE

  // epilogue: C/D layout col = lane&15, row = quad*4 + reg
  float bv[4];
#pragma unroll
  for (int j = 0; j < 4; ++j) bv[j] = bias[n0 + wc * 64 + j * 16 + r16];
#pragma unroll
  for (int i = 0; i < 8; ++i) {
    const int gm = m0 + wr * 128 + i * 16 + quad * 4;
#pragma unroll
    for (int j = 0; j < 4; ++j) {
      float* cp = C + (size_t)gm * NDIM + (n0 + wc * 64 + j * 16 + r16);
#pragma unroll
      for (int r = 0; r < 4; ++r)
        cp[(size_t)r * NDIM] = acc[i][j][r] + bv[j];
    }
  }
}

// ---------------- fallback (ws too small): fused naive ----------------
__global__ __launch_bounds__(256) void fused_fallback(const float* __restrict__ x,
                                                      const int* __restrict__ packed,
                                                      const float* __restrict__ scales,
                                                      const float* __restrict__ bias,
                                                      float* __restrict__ out) {
  const int n = blockIdx.x * 256 + threadIdx.x;
  const int m = blockIdx.y;
  const float* xr = x + (size_t)m * KDIM;
  const int* pr = packed + (size_t)n * (KDIM / 2);
  const float* sc = scales + (size_t)n * (KDIM / 16);
  float acc = 0.f;
  for (int kb = 0; kb < KDIM / 16; ++kb) {
    float s = sc[kb];
    float part = 0.f;
#pragma unroll
    for (int i = 0; i < 8; ++i) {
      int by = pr[kb * 8 + i] & 255;
      int hi = by >> 4, lo = by & 15;
      float vh = fp4_mag(hi & 7); if (hi & 8) vh = -vh;
      float vl = fp4_mag(lo & 7); if (lo & 8) vl = -vl;
      part += xr[kb * 16 + 2 * i] * vh + xr[kb * 16 + 2 * i + 1] * vl;
    }
    acc += s * part;
  }
  out[(size_t)m * NDIM + n] = acc + bias[n];
}

extern "C" void kernel_launch(void* const* d_in, const int* in_sizes, int n_in,
                              void* d_out, int out_size, void* d_ws, size_t ws_size,
                              hipStream_t stream) {
  const float* x      = (const float*)d_in[0];
  const int*   packed = (const int*)d_in[1];
  const float* scales = (const float*)d_in[2];
  const float* bias   = (const float*)d_in[3];
  float* out = (float*)d_out;

  const size_t needA = (size_t)MDIM * KDIM * 2;   // 64 MB bf16 x
  const size_t needW = (size_t)NDIM * KDIM * 2;   // 32 MB bf16 w

  if (ws_size >= needA + needW) {
    unsigned short* xb = (unsigned short*)d_ws;
    unsigned short* wb = (unsigned short*)((char*)d_ws + needA);
    conv_x_kernel<<<(MDIM * KDIM / 8) / 256, 256, 0, stream>>>(x, xb);
    dequant_kernel<<<(NDIM * KDIM / 16) / 256, 256, 0, stream>>>(packed, scales, wb);
    dim3 grid((MDIM / 256) * (NDIM / 256));       // 512 wgs, XCD-swizzled in-kernel
    gemm256_kernel<<<grid, 512, 0, stream>>>((const __bf16*)xb, (const __bf16*)wb, bias, out);
  } else {
    dim3 grid(NDIM / 256, MDIM);
    fused_fallback<<<grid, 256, 0, stream>>>(x, packed, scales, bias, out);
  }
}